// Round 10
// baseline (7272.930 us; speedup 1.0000x reference)
//
#include <hip/hip_runtime.h>
#include <math.h>

// Problem dims (fixed): N=64, T=512, D=512, H=512, 4H=2048 gate cols.
// Gate-col permutation: v = hd*4 + gate  (orig col o = gate*512 + hd)
//
// PANEL (fragment-major) layout for all MFMA operands, 16-row tiles, K=512:
//   flat(rt, kblk, lane, e) = (rt*16 + kblk)*512 + lane*8 + e
//   where rt = row>>4, kblk = k>>5, lane = ((k>>3)&3)*16 + (row&15), e = k&7.
// A fragment load is 64 lanes x 16B CONTIGUOUS (8 cache lines/instr).
constexpr int T_ = 512;
constexpr int H_ = 512;
constexpr int V_ = 2048;
constexpr int KW_ = 512;

using short8 = __attribute__((ext_vector_type(8))) short;     // 8 bf16 MFMA frag
using f32x4  = __attribute__((ext_vector_type(4))) float;     // MFMA acc
using u16x4  = __attribute__((ext_vector_type(4))) unsigned short;
using u16x8  = __attribute__((ext_vector_type(8))) unsigned short;
typedef unsigned long long ull;

// ws layout (bytes):
//   [0, 4MB)        WxT panels bf16: hi then lo (each 1M shorts = 2MB)
//   [4MB, 8MB)      WhT panels bf16: hi then lo
//   [8MB, +256KB)   hstage: [2 parities][hi 32768 | lo 32768 shorts] panel layout
//   [+128KB)        cs: fp32 c[64][512]
//   [+16KB)         flags: int[4096] (64 WG flags, stride 32)
//   xs: panel bf16 x chunk: hi [CT*4 rt][16][512] then lo   (CT*128KB)
//   xw: fp32 [CT*64][2048]                                  (CT*512KB)
constexpr size_t OFF_WXT   = 0;
constexpr size_t OFF_WHT   = 4u * 1024 * 1024;
constexpr size_t OFF_HS    = 8u * 1024 * 1024;
constexpr size_t OFF_CS    = OFF_HS + 256u * 1024;
constexpr size_t OFF_FLAGS = OFF_CS + 128u * 1024;
constexpr size_t OFF_XS    = OFF_FLAGS + 16u * 1024;
constexpr int    NFLAGS    = 4096;

__device__ __forceinline__ void split_bf16(float x, unsigned short& hi, unsigned short& lo) {
    unsigned u  = __builtin_bit_cast(unsigned, x);
    unsigned rh = (u + 0x7fffu + ((u >> 16) & 1u)) >> 16;
    hi = (unsigned short)rh;
    float hf = __builtin_bit_cast(float, rh << 16);
    float l  = x - hf;                       // exact in fp32
    unsigned ul = __builtin_bit_cast(unsigned, l);
    unsigned rl = (ul + 0x7fffu + ((ul >> 16) & 1u)) >> 16;
    lo = (unsigned short)rl;
}

__device__ __forceinline__ float sigm(float x) { return 1.0f / (1.0f + __expf(-x)); }
__device__ __forceinline__ float tanh_fast(float x) {
    float xc = fminf(fmaxf(x, -15.0f), 15.0f);
    float e = __expf(-2.0f * xc);
    return (1.0f - e) / (1.0f + e);
}

// panel flat index
__device__ __forceinline__ size_t pidx(int row, int k) {
    return (size_t)((row >> 4) * 16 + (k >> 5)) * 512 + (((k >> 3) & 3) * 16 + (row & 15)) * 8 + (k & 7);
}

// ---------------------------------------------------------------------------
// prep_wt: W (512 k x 2048 o fp32) -> panel bf16 hi/lo with v-permuted rows.
// ---------------------------------------------------------------------------
__global__ __launch_bounds__(256) void prep_wt(const float* __restrict__ W,
                                               unsigned short* __restrict__ WT_hi,
                                               unsigned short* __restrict__ WT_lo) {
    __shared__ float tile[32][33];
    const int ot = blockIdx.x;          // o-tile (64)
    const int kt = blockIdx.y;          // k-tile (16)
    const int lx = threadIdx.x;         // 0..31
    const int ly = threadIdx.y;         // 0..7
    #pragma unroll
    for (int i = 0; i < 4; ++i) {
        const int k = kt * 32 + ly + i * 8;
        const int o = ot * 32 + lx;
        tile[ly + i * 8][lx] = W[(size_t)k * V_ + o];
    }
    __syncthreads();
    #pragma unroll
    for (int i = 0; i < 4; ++i) {
        const int o = ot * 32 + ly + i * 8;
        const int v = ((o & 511) << 2) | (o >> 9);      // permuted row
        const int kk = kt * 32 + lx;
        unsigned short hi, lo;
        split_bf16(tile[lx][ly + i * 8], hi, lo);
        const size_t d = pidx(v, kk);
        WT_hi[d] = hi;
        WT_lo[d] = lo;
    }
}

// prep_h0: h0 (64x512 fp32) -> hstage parity-0 panels; zero cs + flags.
__global__ __launch_bounds__(256) void prep_h0(const float* __restrict__ h0,
                                               unsigned short* __restrict__ hs,
                                               float* __restrict__ cs,
                                               int* __restrict__ flags) {
    const int i = blockIdx.x * 256 + threadIdx.x;   // 0..32767
    const int n = i >> 9, hd = i & 511;
    unsigned short hi, lo;
    split_bf16(h0[i], hi, lo);
    const size_t d = pidx(n, hd);
    hs[d] = hi;
    hs[32768 + d] = lo;
    cs[i] = 0.0f;
    if (i < NFLAGS) flags[i] = 0;
}

// ---------------------------------------------------------------------------
// xsplit: x chunk [c0,c0+CT) -> panel bf16 hi/lo (dest-linear stores).
// ---------------------------------------------------------------------------
__global__ __launch_bounds__(256) void xsplit(const float* __restrict__ x,
                                              unsigned short* __restrict__ xs,
                                              int c0, int CT) {
    const int gtid = blockIdx.x * 256 + threadIdx.x;
    const size_t xs_lo = (size_t)CT * 32768;
    const int tot = CT * 4096;                   // 8-elem groups
    for (int g = gtid; g < tot; g += 65536) {
        const int lane = g & 63;
        const int rtk  = g >> 6;
        const int kblk = rtk & 15;
        const int rt   = rtk >> 4;
        const int mc = lane & 15, kb = lane >> 4;
        const int r = rt * 16 + mc;              // tl*64 + n
        const int tl = r >> 6, n = r & 63;
        const int k0 = kblk * 32 + kb * 8;
        const float* xp = x + ((size_t)n * T_ + (c0 + tl)) * 512 + k0;
        const float4 va = *(const float4*)xp;
        const float4 vb = *(const float4*)(xp + 4);
        unsigned short hh[8], ll[8];
        split_bf16(va.x, hh[0], ll[0]); split_bf16(va.y, hh[1], ll[1]);
        split_bf16(va.z, hh[2], ll[2]); split_bf16(va.w, hh[3], ll[3]);
        split_bf16(vb.x, hh[4], ll[4]); split_bf16(vb.y, hh[5], ll[5]);
        split_bf16(vb.z, hh[6], ll[6]); split_bf16(vb.w, hh[7], ll[7]);
        u16x8 vh = {hh[0],hh[1],hh[2],hh[3],hh[4],hh[5],hh[6],hh[7]};
        u16x8 vl = {ll[0],ll[1],ll[2],ll[3],ll[4],ll[5],ll[6],ll[7]};
        *(u16x8*)(xs + (size_t)g * 8) = vh;
        *(u16x8*)(xs + xs_lo + (size_t)g * 8) = vl;
    }
}

// ---------------------------------------------------------------------------
// xw_gemm: xw[r][v] = xs[r][:] @ WxT[v][:] + b[v]   (split-bf16, 3-product)
// Panel A/B loads; C stored via per-wave LDS tile -> coalesced dwordx4.
// ---------------------------------------------------------------------------
__global__ __launch_bounds__(256, 1) void xw_gemm(const unsigned short* __restrict__ xs,
                                                  const unsigned short* __restrict__ wxt,
                                                  const float* __restrict__ bias,
                                                  float* __restrict__ xw, int CT) {
    const int tid = threadIdx.x;
    const int wid = tid >> 6, lane = tid & 63;
    const int mc = lane & 15, kb = lane >> 4;
    const int gwave = blockIdx.x * 4 + wid;
    const size_t xs_lo = (size_t)CT * 32768;

    __shared__ float ct[4][16][68];              // per-wave C tile

    const int tiles = CT * 128;                  // (CT*4 row-tiles) x 32 col64-groups
    for (int idx = gwave; idx < tiles; idx += 1024) {
        const int mtA = idx >> 5;
        const int ng  = idx & 31;
        const short* pa  = (const short*)xs + (size_t)mtA * 8192 + lane * 8;
        const short* pal = pa + xs_lo;
        const short* pb  = (const short*)wxt + (size_t)(ng * 4) * 8192 + lane * 8;
        f32x4 acc[4] = {};
        #pragma unroll
        for (int ks = 0; ks < 16; ++ks) {
            const short8 Ah = *(const short8*)(pa + ks * 512);
            const short8 Al = *(const short8*)(pal + ks * 512);
            #pragma unroll
            for (int n2 = 0; n2 < 4; ++n2) {
                const short8 bh = *(const short8*)(pb + (size_t)n2 * 8192 + ks * 512);
                const short8 bl = *(const short8*)(pb + 1048576 + (size_t)n2 * 8192 + ks * 512);
                acc[n2] = __builtin_amdgcn_mfma_f32_16x16x32_bf16(Ah, bh, acc[n2], 0, 0, 0);
                acc[n2] = __builtin_amdgcn_mfma_f32_16x16x32_bf16(Al, bh, acc[n2], 0, 0, 0);
                acc[n2] = __builtin_amdgcn_mfma_f32_16x16x32_bf16(Ah, bl, acc[n2], 0, 0, 0);
            }
        }
        #pragma unroll
        for (int n2 = 0; n2 < 4; ++n2) {
            const int v = ng * 64 + n2 * 16 + mc;
            const float bv = bias[((v & 3) << 9) | (v >> 2)];
            #pragma unroll
            for (int j = 0; j < 4; ++j)
                ct[wid][kb * 4 + j][n2 * 16 + mc] = acc[n2][j] + bv;
        }
        #pragma unroll
        for (int s = 0; s < 4; ++s) {
            const int row16 = s * 4 + (lane >> 4);
            const int col4  = (lane & 15) * 4;
            const float4 cv = *(const float4*)&ct[wid][row16][col4];
            *(float4*)(xw + (size_t)(mtA * 16 + row16) * V_ + ng * 64 + col4) = cv;
        }
    }
}

// ---------------------------------------------------------------------------
// lstm_chunk: CT recurrent steps, ONE cooperative kernel. 64 WGs x 256 thr.
// Changes vs R9: all serial-path stores (h hi/lo, out) are WRITE-THROUGH
// agent-scope atomic 8B stores -> no dirty L2 lines -> the per-step release
// wbl2 walks a clean cache and nothing round-trips to HBM; post-inv reads hit
// MALL. Gate phase: 128 threads x (1 row, 4 consecutive hd) so stores are 8B.
// Barrier protocol byte-identical to R6/R8/R9 (proven 3x).
// ---------------------------------------------------------------------------
__global__ __launch_bounds__(256, 1) void lstm_chunk(const unsigned short* __restrict__ wht,
                                                     unsigned short* __restrict__ hs,
                                                     float* __restrict__ cs,
                                                     const float* __restrict__ xw,
                                                     float* __restrict__ out,
                                                     int* __restrict__ flags,
                                                     int c0, int CT) {
    const int tid = threadIdx.x;
    const int wid = tid >> 6, lane = tid & 63;
    const int wg = blockIdx.x;           // 0..63

    __shared__ float red[4][64][36];

    // ---- load Wh panel fragments and PIN them in registers ----
    short8 Bh[4][2], Bl[4][2];           // [ks][nt]
    #pragma unroll
    for (int ks = 0; ks < 4; ++ks) {
        #pragma unroll
        for (int nt = 0; nt < 2; ++nt) {
            const size_t bo = (size_t)((wg * 2 + nt) * 16 + wid * 4 + ks) * 512 + lane * 8;
            Bh[ks][nt] = *(const short8*)((const short*)wht + bo);
            Bl[ks][nt] = *(const short8*)((const short*)wht + 1048576 + bo);
            asm volatile("" : "+v"(Bh[ks][nt]));   // opaque: remat of the load is illegal
            asm volatile("" : "+v"(Bl[ks][nt]));
        }
    }

    // ---- gate-phase ownership (tid<128): row r2 = tid>>1, hd = wg*8 + half2*4 + i ----
    const int r2 = tid >> 1, half2 = tid & 1;
    f32x4 creg = {0.0f, 0.0f, 0.0f, 0.0f};
    if (tid < 128)
        creg = *(const f32x4*)(cs + (size_t)r2 * 512 + wg * 8 + half2 * 4);
    // h panel write base for (n=r2, hd = wg*8 + half2*4 + i), i=0..3 contiguous
    const size_t hwb = (size_t)((r2 >> 4) * 16 + (wg >> 2)) * 512
                     + ((wg & 3) * 16 + (r2 & 15)) * 8 + half2 * 4;

    for (int tl = 0; tl < CT; ++tl) {
        const int t = c0 + tl;
        const short* hbase = (const short*)(hs + (size_t)(t & 1) * 65536);

        // step-top prefetch of this thread's xw slice (64B, overlaps h/MFMA)
        f32x4 xg[4];
        if (tid < 128) {
            const float* xwr = xw + ((size_t)tl * 64 + r2) * V_ + wg * 32 + half2 * 16;
            #pragma unroll
            for (int i = 0; i < 4; ++i) xg[i] = *(const f32x4*)(xwr + i * 4);
        }

        f32x4 acc[4][2] = {};
        #pragma unroll
        for (int ks = 0; ks < 4; ++ks) {
            #pragma unroll
            for (int rt = 0; rt < 4; ++rt) {
                const size_t ao = (size_t)(rt * 16 + wid * 4 + ks) * 512 + lane * 8;
                const short8 Ah = *(const short8*)(hbase + ao);
                const short8 Al = *(const short8*)(hbase + 32768 + ao);
                #pragma unroll
                for (int nt = 0; nt < 2; ++nt) {
                    acc[rt][nt] = __builtin_amdgcn_mfma_f32_16x16x32_bf16(Ah, Bh[ks][nt], acc[rt][nt], 0, 0, 0);
                    acc[rt][nt] = __builtin_amdgcn_mfma_f32_16x16x32_bf16(Al, Bh[ks][nt], acc[rt][nt], 0, 0, 0);
                    acc[rt][nt] = __builtin_amdgcn_mfma_f32_16x16x32_bf16(Ah, Bl[ks][nt], acc[rt][nt], 0, 0, 0);
                }
            }
        }
        // K-quarter partials -> LDS (C layout: row = kb*4+j, col = mc)
        {
            const int mc = lane & 15, kb = lane >> 4;
            #pragma unroll
            for (int rt = 0; rt < 4; ++rt)
                #pragma unroll
                for (int nt = 0; nt < 2; ++nt)
                    #pragma unroll
                    for (int j = 0; j < 4; ++j)
                        red[wid][rt * 16 + kb * 4 + j][nt * 16 + mc] = acc[rt][nt][j];
        }
        __syncthreads();

        // gates: 128 threads, 4 consecutive hd each; 8B write-through stores
        if (tid < 128) {
            float hv[4];
            #pragma unroll
            for (int i = 0; i < 4; ++i) {
                const int cbase = half2 * 16 + i * 4;
                f32x4 av = *(const f32x4*)&red[0][r2][cbase];
                av += *(const f32x4*)&red[1][r2][cbase];
                av += *(const f32x4*)&red[2][r2][cbase];
                av += *(const f32x4*)&red[3][r2][cbase];
                const float iv = sigm(av[0] + xg[i][0]);
                const float fv = sigm(av[1] + xg[i][1]);
                const float ov = sigm(av[2] + xg[i][2]);
                const float gv = tanh_fast(av[3] + xg[i][3]);
                const float cc = fv * creg[i] + iv * gv;
                creg[i] = cc;
                hv[i] = ov * tanh_fast(cc);
            }
            // out: 16B as two 8B write-through stores
            ull* op = (ull*)(out + ((size_t)r2 * T_ + t) * H_ + wg * 8 + half2 * 4);
            double2 od = {0, 0};
            float2 o01 = {hv[0], hv[1]}, o23 = {hv[2], hv[3]};
            __hip_atomic_store(op,     __builtin_bit_cast(ull, o01),
                               __ATOMIC_RELAXED, __HIP_MEMORY_SCOPE_AGENT);
            __hip_atomic_store(op + 1, __builtin_bit_cast(ull, o23),
                               __ATOMIC_RELAXED, __HIP_MEMORY_SCOPE_AGENT);
            (void)od;
            // h: hi/lo 8B write-through stores (4 contiguous shorts each)
            unsigned short hh[4], hl[4];
            #pragma unroll
            for (int i = 0; i < 4; ++i) split_bf16(hv[i], hh[i], hl[i]);
            u16x4 vh = {hh[0], hh[1], hh[2], hh[3]};
            u16x4 vl = {hl[0], hl[1], hl[2], hl[3]};
            unsigned short* hdst = hs + (size_t)((t + 1) & 1) * 65536 + hwb;
            __hip_atomic_store((ull*)hdst, __builtin_bit_cast(ull, vh),
                               __ATOMIC_RELAXED, __HIP_MEMORY_SCOPE_AGENT);
            __hip_atomic_store((ull*)(hdst + 32768), __builtin_bit_cast(ull, vl),
                               __ATOMIC_RELAXED, __HIP_MEMORY_SCOPE_AGENT);
        }
        __syncthreads();   // red[] reuse safety for next step

        // ---- step barrier (R6/R8/R9 protocol, unchanged) ----
        __threadfence();                       // release: waitcnt + L2 writeback (clean now)
        __syncthreads();
        if (tid == 0)
            __hip_atomic_store(&flags[wg * 32], t + 1,
                               __ATOMIC_RELAXED, __HIP_MEMORY_SCOPE_AGENT);
        bool mine = true;
        do {
            if (tid < 64) {
                int v = __hip_atomic_load(&flags[tid * 32],
                                          __ATOMIC_RELAXED, __HIP_MEMORY_SCOPE_AGENT);
                mine = (v >= t + 1);
                if (!mine) __builtin_amdgcn_s_sleep(2);
            }
        } while (!__syncthreads_and(mine));
        __builtin_amdgcn_fence(__ATOMIC_ACQUIRE, "agent");   // invalidate stale L1/L2
        __syncthreads();
    }

    if (tid < 128)
        *(f32x4*)(cs + (size_t)r2 * 512 + wg * 8 + half2 * 4) = creg;
}

extern "C" void kernel_launch(void* const* d_in, const int* in_sizes, int n_in,
                              void* d_out, int out_size, void* d_ws, size_t ws_size,
                              hipStream_t stream) {
    const float* x  = (const float*)d_in[0];   // (N,T,D)
    const float* h0 = (const float*)d_in[1];   // (N,H)
    const float* Wx = (const float*)d_in[2];   // (D,4H)
    const float* Wh = (const float*)d_in[3];   // (H,4H)
    const float* b  = (const float*)d_in[4];   // (4H,)
    float* out = (float*)d_out;                // (N,T,H)

    char* ws = (char*)d_ws;
    unsigned short* wxt = (unsigned short*)(ws + OFF_WXT);   // hi; lo at +1048576 elems
    unsigned short* wht = (unsigned short*)(ws + OFF_WHT);
    unsigned short* hs  = (unsigned short*)(ws + OFF_HS);
    float* cs           = (float*)(ws + OFF_CS);
    int* flags          = (int*)(ws + OFF_FLAGS);
    unsigned short* xs  = (unsigned short*)(ws + OFF_XS);

    // CT capped at 128 so xw (CT*512KB = 64MB) stays MALL-resident
    int CT = 8;
    const int cands[5] = {128, 64, 32, 16, 8};
    for (int i = 0; i < 5; ++i) {
        size_t need = OFF_XS + (size_t)cands[i] * (131072 + 524288);
        if (need <= ws_size) { CT = cands[i]; break; }
    }
    float* xw = (float*)(ws + OFF_XS + (size_t)CT * 131072);

    prep_wt<<<dim3(64, 16), dim3(32, 8), 0, stream>>>(Wx, wxt, wxt + (size_t)V_ * KW_);
    prep_wt<<<dim3(64, 16), dim3(32, 8), 0, stream>>>(Wh, wht, wht + (size_t)V_ * KW_);
    prep_h0<<<128, 256, 0, stream>>>(h0, hs, cs, flags);

    for (int c0 = 0; c0 < T_; c0 += CT) {
        xsplit<<<256, 256, 0, stream>>>(x, xs, c0, CT);
        xw_gemm<<<256, 256, 0, stream>>>(xs, wxt, b, xw, CT);
        int cc0 = c0, cct = CT;
        void* kwh = (void*)wht; void* khs = (void*)hs; void* kcs = (void*)cs;
        void* kxw = (void*)xw; void* ko = (void*)out; void* kfl = (void*)flags;
        void* args[] = { &kwh, &khs, &kcs, &kxw, &ko, &kfl, &cc0, &cct };
        (void)hipLaunchCooperativeKernel((void*)lstm_chunk, dim3(64), dim3(256), args, 0, stream);
    }
}

// Round 11
// 6799.828 us; speedup vs baseline: 1.0696x; 1.0696x over previous
//
#include <hip/hip_runtime.h>
#include <math.h>

// Problem dims (fixed): N=64, T=512, D=512, H=512, 4H=2048 gate cols.
// Gate-col permutation: v = hd*4 + gate  (orig col o = gate*512 + hd)
//
// PANEL (fragment-major) layout for all MFMA operands, 16-row tiles, K=512:
//   flat(rt, kblk, lane, e) = (rt*16 + kblk)*512 + lane*8 + e
//   where rt = row>>4, kblk = k>>5, lane = ((k>>3)&3)*16 + (row&15), e = k&7.
// A fragment load is 64 lanes x 16B CONTIGUOUS (8 cache lines/instr).
constexpr int T_ = 512;
constexpr int H_ = 512;
constexpr int V_ = 2048;
constexpr int KW_ = 512;

using short8 = __attribute__((ext_vector_type(8))) short;     // 8 bf16 MFMA frag
using f32x4  = __attribute__((ext_vector_type(4))) float;     // MFMA acc
using u16x4  = __attribute__((ext_vector_type(4))) unsigned short;
using u16x8  = __attribute__((ext_vector_type(8))) unsigned short;
typedef unsigned long long ull;

// ws layout (bytes):
//   [0, 4MB)        WxT panels bf16: hi then lo (each 1M shorts = 2MB)
//   [4MB, 8MB)      WhT panels bf16: hi then lo
//   [8MB, +256KB)   hstage: [2 parities][hi 32768 | lo 32768 shorts] panel layout
//   [+128KB)        cs: fp32 c[64][512]
//   [+16KB)         flags: int[4096] (64 WG flags, stride 32)
//   xs: panel bf16 x chunk: hi [CT*4 rt][16][512] then lo   (CT*128KB)
//   xw: fp32 [CT*64][2048]                                  (CT*512KB)
constexpr size_t OFF_WXT   = 0;
constexpr size_t OFF_WHT   = 4u * 1024 * 1024;
constexpr size_t OFF_HS    = 8u * 1024 * 1024;
constexpr size_t OFF_CS    = OFF_HS + 256u * 1024;
constexpr size_t OFF_FLAGS = OFF_CS + 128u * 1024;
constexpr size_t OFF_XS    = OFF_FLAGS + 16u * 1024;
constexpr int    NFLAGS    = 4096;

__device__ __forceinline__ void split_bf16(float x, unsigned short& hi, unsigned short& lo) {
    unsigned u  = __builtin_bit_cast(unsigned, x);
    unsigned rh = (u + 0x7fffu + ((u >> 16) & 1u)) >> 16;
    hi = (unsigned short)rh;
    float hf = __builtin_bit_cast(float, rh << 16);
    float l  = x - hf;                       // exact in fp32
    unsigned ul = __builtin_bit_cast(unsigned, l);
    unsigned rl = (ul + 0x7fffu + ((ul >> 16) & 1u)) >> 16;
    lo = (unsigned short)rl;
}

__device__ __forceinline__ float sigm(float x) { return 1.0f / (1.0f + __expf(-x)); }
__device__ __forceinline__ float tanh_fast(float x) {
    float xc = fminf(fmaxf(x, -15.0f), 15.0f);
    float e = __expf(-2.0f * xc);
    return (1.0f - e) / (1.0f + e);
}

// panel flat index
__device__ __forceinline__ size_t pidx(int row, int k) {
    return (size_t)((row >> 4) * 16 + (k >> 5)) * 512 + (((k >> 3) & 3) * 16 + (row & 15)) * 8 + (k & 7);
}

// ---------------------------------------------------------------------------
// prep_wt: W (512 k x 2048 o fp32) -> panel bf16 hi/lo with v-permuted rows.
// ---------------------------------------------------------------------------
__global__ __launch_bounds__(256) void prep_wt(const float* __restrict__ W,
                                               unsigned short* __restrict__ WT_hi,
                                               unsigned short* __restrict__ WT_lo) {
    __shared__ float tile[32][33];
    const int ot = blockIdx.x;          // o-tile (64)
    const int kt = blockIdx.y;          // k-tile (16)
    const int lx = threadIdx.x;         // 0..31
    const int ly = threadIdx.y;         // 0..7
    #pragma unroll
    for (int i = 0; i < 4; ++i) {
        const int k = kt * 32 + ly + i * 8;
        const int o = ot * 32 + lx;
        tile[ly + i * 8][lx] = W[(size_t)k * V_ + o];
    }
    __syncthreads();
    #pragma unroll
    for (int i = 0; i < 4; ++i) {
        const int o = ot * 32 + ly + i * 8;
        const int v = ((o & 511) << 2) | (o >> 9);      // permuted row
        const int kk = kt * 32 + lx;
        unsigned short hi, lo;
        split_bf16(tile[lx][ly + i * 8], hi, lo);
        const size_t d = pidx(v, kk);
        WT_hi[d] = hi;
        WT_lo[d] = lo;
    }
}

// prep_h0: h0 (64x512 fp32) -> hstage parity-0 panels; zero cs + flags.
__global__ __launch_bounds__(256) void prep_h0(const float* __restrict__ h0,
                                               unsigned short* __restrict__ hs,
                                               float* __restrict__ cs,
                                               int* __restrict__ flags) {
    const int i = blockIdx.x * 256 + threadIdx.x;   // 0..32767
    const int n = i >> 9, hd = i & 511;
    unsigned short hi, lo;
    split_bf16(h0[i], hi, lo);
    const size_t d = pidx(n, hd);
    hs[d] = hi;
    hs[32768 + d] = lo;
    cs[i] = 0.0f;
    if (i < NFLAGS) flags[i] = 0;
}

// ---------------------------------------------------------------------------
// xsplit: x chunk [c0,c0+CT) -> panel bf16 hi/lo (dest-linear stores).
// ---------------------------------------------------------------------------
__global__ __launch_bounds__(256) void xsplit(const float* __restrict__ x,
                                              unsigned short* __restrict__ xs,
                                              int c0, int CT) {
    const int gtid = blockIdx.x * 256 + threadIdx.x;
    const size_t xs_lo = (size_t)CT * 32768;
    const int tot = CT * 4096;                   // 8-elem groups
    for (int g = gtid; g < tot; g += 65536) {
        const int lane = g & 63;
        const int rtk  = g >> 6;
        const int kblk = rtk & 15;
        const int rt   = rtk >> 4;
        const int mc = lane & 15, kb = lane >> 4;
        const int r = rt * 16 + mc;              // tl*64 + n
        const int tl = r >> 6, n = r & 63;
        const int k0 = kblk * 32 + kb * 8;
        const float* xp = x + ((size_t)n * T_ + (c0 + tl)) * 512 + k0;
        const float4 va = *(const float4*)xp;
        const float4 vb = *(const float4*)(xp + 4);
        unsigned short hh[8], ll[8];
        split_bf16(va.x, hh[0], ll[0]); split_bf16(va.y, hh[1], ll[1]);
        split_bf16(va.z, hh[2], ll[2]); split_bf16(va.w, hh[3], ll[3]);
        split_bf16(vb.x, hh[4], ll[4]); split_bf16(vb.y, hh[5], ll[5]);
        split_bf16(vb.z, hh[6], ll[6]); split_bf16(vb.w, hh[7], ll[7]);
        u16x8 vh = {hh[0],hh[1],hh[2],hh[3],hh[4],hh[5],hh[6],hh[7]};
        u16x8 vl = {ll[0],ll[1],ll[2],ll[3],ll[4],ll[5],ll[6],ll[7]};
        *(u16x8*)(xs + (size_t)g * 8) = vh;
        *(u16x8*)(xs + xs_lo + (size_t)g * 8) = vl;
    }
}

// ---------------------------------------------------------------------------
// xw_gemm: xw[r][v] = xs[r][:] @ WxT[v][:] + b[v]   (split-bf16, 3-product)
// Panel A/B loads; C stored via per-wave LDS tile -> coalesced dwordx4.
// ---------------------------------------------------------------------------
__global__ __launch_bounds__(256, 1) void xw_gemm(const unsigned short* __restrict__ xs,
                                                  const unsigned short* __restrict__ wxt,
                                                  const float* __restrict__ bias,
                                                  float* __restrict__ xw, int CT) {
    const int tid = threadIdx.x;
    const int wid = tid >> 6, lane = tid & 63;
    const int mc = lane & 15, kb = lane >> 4;
    const int gwave = blockIdx.x * 4 + wid;
    const size_t xs_lo = (size_t)CT * 32768;

    __shared__ float ct[4][16][68];              // per-wave C tile

    const int tiles = CT * 128;                  // (CT*4 row-tiles) x 32 col64-groups
    for (int idx = gwave; idx < tiles; idx += 1024) {
        const int mtA = idx >> 5;
        const int ng  = idx & 31;
        const short* pa  = (const short*)xs + (size_t)mtA * 8192 + lane * 8;
        const short* pal = pa + xs_lo;
        const short* pb  = (const short*)wxt + (size_t)(ng * 4) * 8192 + lane * 8;
        f32x4 acc[4] = {};
        #pragma unroll
        for (int ks = 0; ks < 16; ++ks) {
            const short8 Ah = *(const short8*)(pa + ks * 512);
            const short8 Al = *(const short8*)(pal + ks * 512);
            #pragma unroll
            for (int n2 = 0; n2 < 4; ++n2) {
                const short8 bh = *(const short8*)(pb + (size_t)n2 * 8192 + ks * 512);
                const short8 bl = *(const short8*)(pb + 1048576 + (size_t)n2 * 8192 + ks * 512);
                acc[n2] = __builtin_amdgcn_mfma_f32_16x16x32_bf16(Ah, bh, acc[n2], 0, 0, 0);
                acc[n2] = __builtin_amdgcn_mfma_f32_16x16x32_bf16(Al, bh, acc[n2], 0, 0, 0);
                acc[n2] = __builtin_amdgcn_mfma_f32_16x16x32_bf16(Ah, bl, acc[n2], 0, 0, 0);
            }
        }
        #pragma unroll
        for (int n2 = 0; n2 < 4; ++n2) {
            const int v = ng * 64 + n2 * 16 + mc;
            const float bv = bias[((v & 3) << 9) | (v >> 2)];
            #pragma unroll
            for (int j = 0; j < 4; ++j)
                ct[wid][kb * 4 + j][n2 * 16 + mc] = acc[n2][j] + bv;
        }
        #pragma unroll
        for (int s = 0; s < 4; ++s) {
            const int row16 = s * 4 + (lane >> 4);
            const int col4  = (lane & 15) * 4;
            const float4 cv = *(const float4*)&ct[wid][row16][col4];
            *(float4*)(xw + (size_t)(mtA * 16 + row16) * V_ + ng * 64 + col4) = cv;
        }
    }
}

// ---------------------------------------------------------------------------
// lstm_chunk: CT recurrent steps, ONE cooperative kernel. 64 WGs x 256 thr.
// Change vs R10 (single, surgical): ALL 32 h-fragment loads (512B/wave) are
// hoisted to the TOP of the step into register arrays, BEFORE any MFMA.
// At launch_bounds(256,1) the wave has ~512 unified VGPRs; 32 frags (128 VGPR)
// + pinned B (64) + acc (32) fit. This collapses ~16 serialized post-inv MALL
// round-trips (the R9/R10 12.7us/step floor) into ONE pipelined latency.
// Everything else (barrier protocol, write-through stores, layouts) is
// byte-identical to R10 (proven correct 3 rounds running).
// ---------------------------------------------------------------------------
__global__ __launch_bounds__(256, 1) void lstm_chunk(const unsigned short* __restrict__ wht,
                                                     unsigned short* __restrict__ hs,
                                                     float* __restrict__ cs,
                                                     const float* __restrict__ xw,
                                                     float* __restrict__ out,
                                                     int* __restrict__ flags,
                                                     int c0, int CT) {
    const int tid = threadIdx.x;
    const int wid = tid >> 6, lane = tid & 63;
    const int wg = blockIdx.x;           // 0..63

    __shared__ float red[4][64][36];

    // ---- load Wh panel fragments and PIN them in registers ----
    short8 Bh[4][2], Bl[4][2];           // [ks][nt]
    #pragma unroll
    for (int ks = 0; ks < 4; ++ks) {
        #pragma unroll
        for (int nt = 0; nt < 2; ++nt) {
            const size_t bo = (size_t)((wg * 2 + nt) * 16 + wid * 4 + ks) * 512 + lane * 8;
            Bh[ks][nt] = *(const short8*)((const short*)wht + bo);
            Bl[ks][nt] = *(const short8*)((const short*)wht + 1048576 + bo);
            asm volatile("" : "+v"(Bh[ks][nt]));   // opaque: remat of the load is illegal
            asm volatile("" : "+v"(Bl[ks][nt]));
        }
    }

    // ---- gate-phase ownership (tid<128): row r2 = tid>>1, hd = wg*8 + half2*4 + i ----
    const int r2 = tid >> 1, half2 = tid & 1;
    f32x4 creg = {0.0f, 0.0f, 0.0f, 0.0f};
    if (tid < 128)
        creg = *(const f32x4*)(cs + (size_t)r2 * 512 + wg * 8 + half2 * 4);
    // h panel write base for (n=r2, hd = wg*8 + half2*4 + i), i=0..3 contiguous
    const size_t hwb = (size_t)((r2 >> 4) * 16 + (wg >> 2)) * 512
                     + ((wg & 3) * 16 + (r2 & 15)) * 8 + half2 * 4;

    for (int tl = 0; tl < CT; ++tl) {
        const int t = c0 + tl;
        const short* hbase = (const short*)(hs + (size_t)(t & 1) * 65536);

        // step-top prefetch of this thread's xw slice (64B, overlaps h loads)
        f32x4 xg[4];
        if (tid < 128) {
            const float* xwr = xw + ((size_t)tl * 64 + r2) * V_ + wg * 32 + half2 * 16;
            #pragma unroll
            for (int i = 0; i < 4; ++i) xg[i] = *(const f32x4*)(xwr + i * 4);
        }

        // ---- ALL h fragments up front: 32 independent 16B loads, one latency ----
        short8 HA[4][4], HL[4][4];       // [ks][rt]
        #pragma unroll
        for (int ks = 0; ks < 4; ++ks) {
            #pragma unroll
            for (int rt = 0; rt < 4; ++rt) {
                const size_t ao = (size_t)(rt * 16 + wid * 4 + ks) * 512 + lane * 8;
                HA[ks][rt] = *(const short8*)(hbase + ao);
                HL[ks][rt] = *(const short8*)(hbase + 32768 + ao);
            }
        }

        f32x4 acc[4][2] = {};
        #pragma unroll
        for (int ks = 0; ks < 4; ++ks) {
            #pragma unroll
            for (int rt = 0; rt < 4; ++rt) {
                #pragma unroll
                for (int nt = 0; nt < 2; ++nt) {
                    acc[rt][nt] = __builtin_amdgcn_mfma_f32_16x16x32_bf16(HA[ks][rt], Bh[ks][nt], acc[rt][nt], 0, 0, 0);
                    acc[rt][nt] = __builtin_amdgcn_mfma_f32_16x16x32_bf16(HL[ks][rt], Bh[ks][nt], acc[rt][nt], 0, 0, 0);
                    acc[rt][nt] = __builtin_amdgcn_mfma_f32_16x16x32_bf16(HA[ks][rt], Bl[ks][nt], acc[rt][nt], 0, 0, 0);
                }
            }
        }
        // K-quarter partials -> LDS (C layout: row = kb*4+j, col = mc)
        {
            const int mc = lane & 15, kb = lane >> 4;
            #pragma unroll
            for (int rt = 0; rt < 4; ++rt)
                #pragma unroll
                for (int nt = 0; nt < 2; ++nt)
                    #pragma unroll
                    for (int j = 0; j < 4; ++j)
                        red[wid][rt * 16 + kb * 4 + j][nt * 16 + mc] = acc[rt][nt][j];
        }
        __syncthreads();

        // gates: 128 threads, 4 consecutive hd each; 8B write-through stores
        if (tid < 128) {
            float hv[4];
            #pragma unroll
            for (int i = 0; i < 4; ++i) {
                const int cbase = half2 * 16 + i * 4;
                f32x4 av = *(const f32x4*)&red[0][r2][cbase];
                av += *(const f32x4*)&red[1][r2][cbase];
                av += *(const f32x4*)&red[2][r2][cbase];
                av += *(const f32x4*)&red[3][r2][cbase];
                const float iv = sigm(av[0] + xg[i][0]);
                const float fv = sigm(av[1] + xg[i][1]);
                const float ov = sigm(av[2] + xg[i][2]);
                const float gv = tanh_fast(av[3] + xg[i][3]);
                const float cc = fv * creg[i] + iv * gv;
                creg[i] = cc;
                hv[i] = ov * tanh_fast(cc);
            }
            // out: 16B as two 8B write-through stores
            ull* op = (ull*)(out + ((size_t)r2 * T_ + t) * H_ + wg * 8 + half2 * 4);
            float2 o01 = {hv[0], hv[1]}, o23 = {hv[2], hv[3]};
            __hip_atomic_store(op,     __builtin_bit_cast(ull, o01),
                               __ATOMIC_RELAXED, __HIP_MEMORY_SCOPE_AGENT);
            __hip_atomic_store(op + 1, __builtin_bit_cast(ull, o23),
                               __ATOMIC_RELAXED, __HIP_MEMORY_SCOPE_AGENT);
            // h: hi/lo 8B write-through stores (4 contiguous shorts each)
            unsigned short hh[4], hl[4];
            #pragma unroll
            for (int i = 0; i < 4; ++i) split_bf16(hv[i], hh[i], hl[i]);
            u16x4 vh = {hh[0], hh[1], hh[2], hh[3]};
            u16x4 vl = {hl[0], hl[1], hl[2], hl[3]};
            unsigned short* hdst = hs + (size_t)((t + 1) & 1) * 65536 + hwb;
            __hip_atomic_store((ull*)hdst, __builtin_bit_cast(ull, vh),
                               __ATOMIC_RELAXED, __HIP_MEMORY_SCOPE_AGENT);
            __hip_atomic_store((ull*)(hdst + 32768), __builtin_bit_cast(ull, vl),
                               __ATOMIC_RELAXED, __HIP_MEMORY_SCOPE_AGENT);
        }
        __syncthreads();   // red[] reuse safety for next step

        // ---- step barrier (R6/R8/R9/R10 protocol, unchanged) ----
        __threadfence();                       // release: waitcnt + L2 writeback (clean)
        __syncthreads();
        if (tid == 0)
            __hip_atomic_store(&flags[wg * 32], t + 1,
                               __ATOMIC_RELAXED, __HIP_MEMORY_SCOPE_AGENT);
        bool mine = true;
        do {
            if (tid < 64) {
                int v = __hip_atomic_load(&flags[tid * 32],
                                          __ATOMIC_RELAXED, __HIP_MEMORY_SCOPE_AGENT);
                mine = (v >= t + 1);
                if (!mine) __builtin_amdgcn_s_sleep(2);
            }
        } while (!__syncthreads_and(mine));
        __builtin_amdgcn_fence(__ATOMIC_ACQUIRE, "agent");   // invalidate stale L1/L2
        __syncthreads();
    }

    if (tid < 128)
        *(f32x4*)(cs + (size_t)r2 * 512 + wg * 8 + half2 * 4) = creg;
}

extern "C" void kernel_launch(void* const* d_in, const int* in_sizes, int n_in,
                              void* d_out, int out_size, void* d_ws, size_t ws_size,
                              hipStream_t stream) {
    const float* x  = (const float*)d_in[0];   // (N,T,D)
    const float* h0 = (const float*)d_in[1];   // (N,H)
    const float* Wx = (const float*)d_in[2];   // (D,4H)
    const float* Wh = (const float*)d_in[3];   // (H,4H)
    const float* b  = (const float*)d_in[4];   // (4H,)
    float* out = (float*)d_out;                // (N,T,H)

    char* ws = (char*)d_ws;
    unsigned short* wxt = (unsigned short*)(ws + OFF_WXT);   // hi; lo at +1048576 elems
    unsigned short* wht = (unsigned short*)(ws + OFF_WHT);
    unsigned short* hs  = (unsigned short*)(ws + OFF_HS);
    float* cs           = (float*)(ws + OFF_CS);
    int* flags          = (int*)(ws + OFF_FLAGS);
    unsigned short* xs  = (unsigned short*)(ws + OFF_XS);

    // CT capped at 128 so xw (CT*512KB = 64MB) stays MALL-resident
    int CT = 8;
    const int cands[5] = {128, 64, 32, 16, 8};
    for (int i = 0; i < 5; ++i) {
        size_t need = OFF_XS + (size_t)cands[i] * (131072 + 524288);
        if (need <= ws_size) { CT = cands[i]; break; }
    }
    float* xw = (float*)(ws + OFF_XS + (size_t)CT * 131072);

    prep_wt<<<dim3(64, 16), dim3(32, 8), 0, stream>>>(Wx, wxt, wxt + (size_t)V_ * KW_);
    prep_wt<<<dim3(64, 16), dim3(32, 8), 0, stream>>>(Wh, wht, wht + (size_t)V_ * KW_);
    prep_h0<<<128, 256, 0, stream>>>(h0, hs, cs, flags);

    for (int c0 = 0; c0 < T_; c0 += CT) {
        xsplit<<<256, 256, 0, stream>>>(x, xs, c0, CT);
        xw_gemm<<<256, 256, 0, stream>>>(xs, wxt, b, xw, CT);
        int cc0 = c0, cct = CT;
        void* kwh = (void*)wht; void* khs = (void*)hs; void* kcs = (void*)cs;
        void* kxw = (void*)xw; void* ko = (void*)out; void* kfl = (void*)flags;
        void* args[] = { &kwh, &khs, &kcs, &kxw, &ko, &kfl, &cc0, &cct };
        (void)hipLaunchCooperativeKernel((void*)lstm_chunk, dim3(64), dim3(256), args, 0, stream);
    }
}